// Round 2
// baseline (7914.091 us; speedup 1.0000x reference)
//
#include <hip/hip_runtime.h>

typedef short v8s __attribute__((ext_vector_type(8)));
typedef float v4f __attribute__((ext_vector_type(4)));

#define S_LEN 1024
#define NH    128
#define DM    7168
#define QL    1536
#define KVL   512
#define DQd   192
#define DVd   128
#define QDIM  (NH * DQd)   // 24576
#define VDIM  (NH * DVd)   // 16384

__device__ __forceinline__ float bf2f(unsigned short u) {
  union { unsigned int i; float f; } x; x.i = ((unsigned int)u) << 16; return x.f;
}
__device__ __forceinline__ unsigned short f2bf(float f) {
  union { float f; unsigned int i; } x; x.f = f;
  unsigned int r = x.i + 0x7fffu + ((x.i >> 16) & 1u);
  return (unsigned short)(r >> 16);
}

// load 8 consecutive f32, round-to-nearest-even to a bf16 MFMA fragment
__device__ __forceinline__ v8s cvt8(const float* __restrict__ p) {
  v4f f0 = *(const v4f*)p;
  v4f f1 = *(const v4f*)(p + 4);
  v8s r; unsigned short* u = (unsigned short*)&r;
#pragma unroll
  for (int i = 0; i < 4; i++) { u[i] = f2bf(f0[i]); u[4 + i] = f2bf(f1[i]); }
  return r;
}

// C[M,N] = A[M,K] * W[N,K]^T. Operand dtypes via template flags
// (true = f32 in global, false = bf16-as-u16). fp32 accumulate.
// Block: 256 thr = 4 waves; wave w does rows [m0+w*16, +16), 64 cols.
// grid.x = N/64, grid.y = M/64.
template<bool AF32, bool WF32, bool CF32>
__global__ __launch_bounds__(256) void gemm_bt(
    const void* __restrict__ Av, int lda,
    const void* __restrict__ Wv, int ldw,
    void* __restrict__ Cv, int ldc, int K)
{
  const int lane = threadIdx.x & 63;
  const int wave = threadIdx.x >> 6;
  const int r15  = lane & 15;
  const int quad = lane >> 4;
  const int m0 = blockIdx.y * 64 + wave * 16;
  const int n0 = blockIdx.x * 64;

  const size_t aoff = (size_t)(m0 + r15) * lda + quad * 8;
  const size_t woff = (size_t)(n0 + r15) * ldw + quad * 8;
  const size_t w16 = (size_t)16 * ldw;

  v4f acc0 = {0.f, 0.f, 0.f, 0.f};
  v4f acc1 = acc0, acc2 = acc0, acc3 = acc0;

  for (int k0 = 0; k0 < K; k0 += 32) {
    v8s a, b0, b1, b2, b3;
    if constexpr (AF32) {
      a = cvt8((const float*)Av + aoff + k0);
    } else {
      a = *(const v8s*)((const unsigned short*)Av + aoff + k0);
    }
    if constexpr (WF32) {
      const float* wp = (const float*)Wv + woff + k0;
      b0 = cvt8(wp);
      b1 = cvt8(wp + w16);
      b2 = cvt8(wp + 2 * w16);
      b3 = cvt8(wp + 3 * w16);
    } else {
      const unsigned short* wp = (const unsigned short*)Wv + woff + k0;
      b0 = *(const v8s*)wp;
      b1 = *(const v8s*)(wp + w16);
      b2 = *(const v8s*)(wp + 2 * w16);
      b3 = *(const v8s*)(wp + 3 * w16);
    }
    acc0 = __builtin_amdgcn_mfma_f32_16x16x32_bf16(a, b0, acc0, 0, 0, 0);
    acc1 = __builtin_amdgcn_mfma_f32_16x16x32_bf16(a, b1, acc1, 0, 0, 0);
    acc2 = __builtin_amdgcn_mfma_f32_16x16x32_bf16(a, b2, acc2, 0, 0, 0);
    acc3 = __builtin_amdgcn_mfma_f32_16x16x32_bf16(a, b3, acc3, 0, 0, 0);
  }

  const int row = m0 + quad * 4;
  if constexpr (CF32) {
    float* Crow = (float*)Cv + n0 + r15;
#pragma unroll
    for (int r = 0; r < 4; r++) {
      float* cp = Crow + (size_t)(row + r) * ldc;
      cp[0]  = acc0[r];
      cp[16] = acc1[r];
      cp[32] = acc2[r];
      cp[48] = acc3[r];
    }
  } else {
    unsigned short* Crow = (unsigned short*)Cv + n0 + r15;
#pragma unroll
    for (int r = 0; r < 4; r++) {
      unsigned short* cp = Crow + (size_t)(row + r) * ldc;
      cp[0]  = f2bf(acc0[r]);
      cp[16] = f2bf(acc1[r]);
      cp[32] = f2bf(acc2[r]);
      cp[48] = f2bf(acc3[r]);
    }
  }
}

// In-place RoPE on q (cols 128..191 of each 192-col head) and k (bf16 ws).
// Pair i in [0,32): angle = pos * 10000^(-((2i) mod 32)/32).
__global__ void rope_kernel(unsigned short* __restrict__ q,
                            unsigned short* __restrict__ k)
{
  int idx = blockIdx.x * blockDim.x + threadIdx.x;  // S*NH*32 = 4194304
  int i = idx & 31;
  int h = (idx >> 5) & (NH - 1);
  int s = idx >> 12;
  int j = (2 * i) & 31;
  float freq = powf(10000.0f, -(float)j / 32.0f);
  float ang = (float)s * freq;
  float c = cosf(ang), sn = sinf(ang);
  size_t base = (size_t)s * QDIM + h * DQd + 128 + 2 * i;

  float t0 = bf2f(q[base]), t1 = bf2f(q[base + 1]);
  q[base]     = f2bf(t0 * c - t1 * sn);
  q[base + 1] = f2bf(t0 * sn + t1 * c);

  t0 = bf2f(k[base]); t1 = bf2f(k[base + 1]);
  k[base]     = f2bf(t0 * c - t1 * sn);
  k[base + 1] = f2bf(t0 * sn + t1 * c);
}

// Fused attention for one (head, 16 q-rows) tile. Full (non-causal) softmax.
// Two-pass (rowmax then exp+rowsum) so scores live only in registers;
// P stored bf16 in LDS; PV via MFMA with V staged through LDS.
// grid: (S/16, NH), block 256 (4 waves).
__global__ __launch_bounds__(256) void attn_kernel(
    const unsigned short* __restrict__ qb,
    const unsigned short* __restrict__ kb,
    const unsigned short* __restrict__ vb,
    unsigned short* __restrict__ ao)
{
  __shared__ unsigned short p_lds[16][1048];   // P tile, stride 1048 (bank spread)
  __shared__ unsigned short v_lds[64][130];    // V chunk, stride 130
  __shared__ float redbuf[4][16];
  __shared__ float rowmax[16];
  __shared__ float rowinv[16];

  const int h  = blockIdx.y;
  const int q0 = blockIdx.x * 16;
  const int t = threadIdx.x;
  const int lane = t & 63;
  const int wave = t >> 6;
  const int r15  = lane & 15;
  const int quad = lane >> 4;
  const float scale = 0.07216878364870323f;  // 1/sqrt(192)

  // Hoisted Q fragments (A-operand: row = lane&15, k = quad*8 + j)
  v8s afr[6];
  {
    const unsigned short* qrow = qb + (size_t)(q0 + r15) * QDIM + h * DQd + quad * 8;
#pragma unroll
    for (int kk = 0; kk < 6; kk++) afr[kk] = *(const v8s*)(qrow + kk * 32);
  }

  // ---- Pass 1: row maxima ----
  float vmax[4] = {-1e30f, -1e30f, -1e30f, -1e30f};
  for (int st = wave; st < 64; st += 4) {
    const int k0 = st * 16;
    const unsigned short* krow = kb + (size_t)(k0 + r15) * QDIM + h * DQd + quad * 8;
    v4f acc = {0.f, 0.f, 0.f, 0.f};
#pragma unroll
    for (int kk = 0; kk < 6; kk++) {
      v8s b = *(const v8s*)(krow + kk * 32);
      acc = __builtin_amdgcn_mfma_f32_16x16x32_bf16(afr[kk], b, acc, 0, 0, 0);
    }
#pragma unroll
    for (int r = 0; r < 4; r++) vmax[r] = fmaxf(vmax[r], acc[r]);
  }
#pragma unroll
  for (int mk = 1; mk < 16; mk <<= 1) {
#pragma unroll
    for (int r = 0; r < 4; r++) vmax[r] = fmaxf(vmax[r], __shfl_xor(vmax[r], mk));
  }
  if (r15 == 0) {
#pragma unroll
    for (int r = 0; r < 4; r++) redbuf[wave][quad * 4 + r] = vmax[r];
  }
  __syncthreads();
  if (t < 16) {
    float m = fmaxf(fmaxf(redbuf[0][t], redbuf[1][t]),
                    fmaxf(redbuf[2][t], redbuf[3][t]));
    rowmax[t] = m * scale;
  }
  __syncthreads();

  // ---- Pass 2: recompute scores, exp, store P (bf16), row sums ----
  float mrow[4];
#pragma unroll
  for (int r = 0; r < 4; r++) mrow[r] = rowmax[quad * 4 + r];
  float vsum[4] = {0.f, 0.f, 0.f, 0.f};
  for (int st = wave; st < 64; st += 4) {
    const int k0 = st * 16;
    const unsigned short* krow = kb + (size_t)(k0 + r15) * QDIM + h * DQd + quad * 8;
    v4f acc = {0.f, 0.f, 0.f, 0.f};
#pragma unroll
    for (int kk = 0; kk < 6; kk++) {
      v8s b = *(const v8s*)(krow + kk * 32);
      acc = __builtin_amdgcn_mfma_f32_16x16x32_bf16(afr[kk], b, acc, 0, 0, 0);
    }
#pragma unroll
    for (int r = 0; r < 4; r++) {
      float p = __expf(acc[r] * scale - mrow[r]);
      unsigned short pb = f2bf(p);
      p_lds[quad * 4 + r][k0 + r15] = pb;
      vsum[r] += bf2f(pb);   // sum the rounded value PV will actually use
    }
  }
#pragma unroll
  for (int mk = 1; mk < 16; mk <<= 1) {
#pragma unroll
    for (int r = 0; r < 4; r++) vsum[r] += __shfl_xor(vsum[r], mk);
  }
  if (r15 == 0) {
#pragma unroll
    for (int r = 0; r < 4; r++) redbuf[wave][quad * 4 + r] = vsum[r];
  }
  __syncthreads();
  if (t < 16) {
    rowinv[t] = 1.0f / (redbuf[0][t] + redbuf[1][t] + redbuf[2][t] + redbuf[3][t]);
  }

  // ---- Phase C: O = P @ V via MFMA, V staged in LDS (16 chunks of 64 k) ----
  v4f oacc0 = {0.f, 0.f, 0.f, 0.f};
  v4f oacc1 = {0.f, 0.f, 0.f, 0.f};
  for (int c = 0; c < 16; c++) {
    __syncthreads();
    // load V chunk [64 k][128 d] cooperatively, 4B at a time
    for (int e = t; e < 64 * 64; e += 256) {
      int kk = e >> 6;
      int d2 = (e & 63) * 2;
      *(unsigned int*)(&v_lds[kk][d2]) =
          *(const unsigned int*)(vb + (size_t)(c * 64 + kk) * VDIM + h * DVd + d2);
    }
    __syncthreads();
#pragma unroll
    for (int ks = 0; ks < 2; ks++) {
      const int kb2 = c * 64 + ks * 32 + quad * 8;
      v8s af = *(const v8s*)(&p_lds[r15][kb2]);
      const int kl = ks * 32 + quad * 8;
#pragma unroll
      for (int ds = 0; ds < 2; ds++) {
        const int d0 = (wave * 2 + ds) * 16;
        v8s bfr;
        unsigned short* bp = (unsigned short*)&bfr;
#pragma unroll
        for (int j = 0; j < 8; j++) bp[j] = v_lds[kl + j][d0 + r15];
        if (ds == 0) oacc0 = __builtin_amdgcn_mfma_f32_16x16x32_bf16(af, bfr, oacc0, 0, 0, 0);
        else         oacc1 = __builtin_amdgcn_mfma_f32_16x16x32_bf16(af, bfr, oacc1, 0, 0, 0);
      }
    }
  }

  // epilogue: C layout col = lane&15, row = quad*4 + r
#pragma unroll
  for (int ds = 0; ds < 2; ds++) {
    const int d0 = (wave * 2 + ds) * 16;
#pragma unroll
    for (int r = 0; r < 4; r++) {
      const int qi = quad * 4 + r;
      float v = (ds == 0 ? oacc0[r] : oacc1[r]) * rowinv[qi];
      ao[(size_t)(q0 + qi) * VDIM + h * DVd + d0 + r15] = f2bf(v);
    }
  }
}

extern "C" void kernel_launch(void* const* d_in, const int* in_sizes, int n_in,
                              void* d_out, int out_size, void* d_ws, size_t ws_size,
                              hipStream_t stream) {
  // inputs are float32 per the reference dtypes
  const float* hidden = (const float*)d_in[0];
  const float* Wqa  = (const float*)d_in[1];
  const float* Wkva = (const float*)d_in[2];
  const float* Wqb  = (const float*)d_in[3];
  const float* Wkb  = (const float*)d_in[4];
  const float* Wvb  = (const float*)d_in[5];
  const float* Wo   = (const float*)d_in[6];
  float* out = (float*)d_out;

  // bf16 intermediates in workspace
  unsigned short* ws  = (unsigned short*)d_ws;
  unsigned short* lat = ws;                                   // [1024, 2048]
  unsigned short* qb  = lat + (size_t)S_LEN * 2048;           // [1024, 24576]
  unsigned short* kb  = qb  + (size_t)S_LEN * QDIM;           // [1024, 24576]
  unsigned short* vb  = kb  + (size_t)S_LEN * QDIM;           // [1024, 16384]
  unsigned short* ao  = vb  + (size_t)S_LEN * VDIM;           // [1024, 16384]

  dim3 blk(256);

  // latent projections: lat[:, :1536] = hidden @ Wqa^T ; lat[:, 1536:] = hidden @ Wkva^T
  gemm_bt<true, true, false><<<dim3(QL / 64, S_LEN / 64), blk, 0, stream>>>(
      hidden, DM, Wqa, DM, lat, 2048, DM);
  gemm_bt<true, true, false><<<dim3(KVL / 64, S_LEN / 64), blk, 0, stream>>>(
      hidden, DM, Wkva, DM, lat + QL, 2048, DM);

  // up-projections (A = bf16 latent, W = f32)
  gemm_bt<false, true, false><<<dim3(QDIM / 64, S_LEN / 64), blk, 0, stream>>>(
      lat, 2048, Wqb, QL, qb, QDIM, QL);
  gemm_bt<false, true, false><<<dim3(QDIM / 64, S_LEN / 64), blk, 0, stream>>>(
      lat + QL, 2048, Wkb, KVL, kb, QDIM, KVL);
  gemm_bt<false, true, false><<<dim3(VDIM / 64, S_LEN / 64), blk, 0, stream>>>(
      lat + QL, 2048, Wvb, KVL, vb, VDIM, KVL);

  // RoPE on q and k rope-halves
  rope_kernel<<<(S_LEN * NH * 32) / 256, blk, 0, stream>>>(qb, kb);

  // fused attention
  attn_kernel<<<dim3(S_LEN / 16, NH), blk, 0, stream>>>(qb, kb, vb, ao);

  // output projection -> d_out (f32)
  gemm_bt<false, true, true><<<dim3(DM / 64, S_LEN / 64), blk, 0, stream>>>(
      ao, VDIM, Wo, VDIM, out, DM, VDIM);
}